// Round 2
// baseline (607.898 us; speedup 1.0000x reference)
//
#include <hip/hip_runtime.h>
#include <hip/hip_bf16.h>

#define M_TOK 8192
#define K_DIM 4096
#define N_DIM 4096

typedef float f32x4 __attribute__((ext_vector_type(4)));
typedef __bf16 bf16x8 __attribute__((ext_vector_type(8)));
typedef unsigned short u16;

__device__ __forceinline__ u16 f2bf(float f) {
    union { float f; unsigned u; } v; v.f = f;
    unsigned r = v.u + 0x7FFF + ((v.u >> 16) & 1);   // RTNE
    return (u16)(r >> 16);
}

__device__ __forceinline__ void gload16(const void* g, void* l) {
    __builtin_amdgcn_global_load_lds(
        (const __attribute__((address_space(1))) unsigned*)g,
        (__attribute__((address_space(3))) unsigned*)l, 16, 0, 0);
}

// ---- pre-pass: x fp32 -> bf16 (identity layout) ----
__global__ __launch_bounds__(256) void cvt_kernel(const float* __restrict__ in,
                                                  u16* __restrict__ out) {
    size_t i = ((size_t)blockIdx.x * 256 + threadIdx.x) * 8;
    const float4* p = (const float4*)(in + i);
    float4 a = p[0], b = p[1];
    union { u16 h[8]; uint4 v; } o;
    o.h[0] = f2bf(a.x); o.h[1] = f2bf(a.y); o.h[2] = f2bf(a.z); o.h[3] = f2bf(a.w);
    o.h[4] = f2bf(b.x); o.h[5] = f2bf(b.y); o.h[6] = f2bf(b.z); o.h[7] = f2bf(b.w);
    *(uint4*)(out + i) = o.v;
}

// ---- pre-pass: W[k][n] fp32 -> Wt[n][k] bf16 (LDS-tiled transpose) ----
__global__ __launch_bounds__(256) void transpose_cvt_kernel(const float* __restrict__ w,
                                                            u16* __restrict__ wt) {
    __shared__ float t[64][65];
    int k0 = blockIdx.x * 64, n0 = blockIdx.y * 64;
    int tx = threadIdx.x & 63, ty = threadIdx.x >> 6;   // 64 x 4
#pragma unroll
    for (int r = 0; r < 64; r += 4)
        t[r + ty][tx] = w[(size_t)(k0 + r + ty) * N_DIM + n0 + tx];
    __syncthreads();
#pragma unroll
    for (int r = 0; r < 64; r += 4)
        wt[(size_t)(n0 + r + ty) * K_DIM + k0 + tx] = f2bf(t[tx][r + ty]);
}

// ---- main GEMM: C[m][n] = sum_k A[m][k]*Bt[n][k] + bias[n] ----
// m97 structure: 128x128 tile, BK=32, 4 waves (2x2, 64x64 each), 16x16x32 bf16 MFMA,
// global_load_lds width=16 staging, single-buffer, 2 barriers / K-step.
__global__ __launch_bounds__(256) void gemm_kernel(const u16* __restrict__ A,   // [M][K] bf16
                                                   const u16* __restrict__ Bt,  // [N][K] bf16
                                                   const float* __restrict__ bias,
                                                   float* __restrict__ C) {
    __shared__ __align__(16) u16 lA[128 * 32];
    __shared__ __align__(16) u16 lB[128 * 32];

    int tid = threadIdx.x;
    int bid = blockIdx.x;
    // XCD-aware swizzle: 2048 blocks, 8 XCDs, 256 blocks/XCD chunk (bijective: 2048 % 8 == 0)
    int swz = (bid & 7) * 256 + (bid >> 3);
    int by = swz >> 5;   // [0,64)  M tiles
    int bx = swz & 31;   // [0,32)  N tiles

    int lane = tid & 63;
    int wid = tid >> 6;
    int wr = wid >> 1, wc = wid & 1;

    // staging: thread covers 16B of tile; row = tid/4, col-group = tid%4
    const u16* ga = A  + (size_t)(by * 128 + (tid >> 2)) * K_DIM + (tid & 3) * 8;
    const u16* gb = Bt + (size_t)(bx * 128 + (tid >> 2)) * K_DIM + (tid & 3) * 8;
    u16* la = &lA[tid * 8];
    u16* lb = &lB[tid * 8];

    f32x4 acc[4][4] = {};

    int frow = lane & 15;
    int kseg = (lane >> 4) * 8;
    const u16* pa = &lA[(wr * 64 + frow) * 32 + kseg];
    const u16* pb = &lB[(wc * 64 + frow) * 32 + kseg];

    for (int kt = 0; kt < K_DIM / 32; ++kt) {
        int ko = kt * 32;
        gload16(ga + ko, la);
        gload16(ga + ko + (size_t)64 * K_DIM, la + 64 * 32);
        gload16(gb + ko, lb);
        gload16(gb + ko + (size_t)64 * K_DIM, lb + 64 * 32);
        __syncthreads();   // compiler drains vmcnt(0) before s_barrier

        bf16x8 af[4], bfv[4];
#pragma unroll
        for (int i = 0; i < 4; ++i) af[i]  = *(const bf16x8*)(pa + i * 16 * 32);
#pragma unroll
        for (int j = 0; j < 4; ++j) bfv[j] = *(const bf16x8*)(pb + j * 16 * 32);
#pragma unroll
        for (int i = 0; i < 4; ++i)
#pragma unroll
            for (int j = 0; j < 4; ++j)
                acc[i][j] = __builtin_amdgcn_mfma_f32_16x16x32_bf16(af[i], bfv[j], acc[i][j], 0, 0, 0);
        __syncthreads();
    }

    // epilogue: C/D layout col = lane&15, row = (lane>>4)*4 + reg  [m89/m91 verified]
    int col0 = bx * 128 + wc * 64 + (lane & 15);
    int row0 = by * 128 + wr * 64 + (lane >> 4) * 4;
    float bcol[4];
#pragma unroll
    for (int j = 0; j < 4; ++j) bcol[j] = bias[col0 + j * 16];
#pragma unroll
    for (int i = 0; i < 4; ++i)
#pragma unroll
        for (int j = 0; j < 4; ++j)
#pragma unroll
            for (int r = 0; r < 4; ++r)
                C[(size_t)(row0 + i * 16 + r) * N_DIM + col0 + j * 16] = acc[i][j][r] + bcol[j];
}

// ---- fallback (only if ws too small): naive fp32 ----
__global__ __launch_bounds__(256) void fallback_kernel(const float* __restrict__ x,
                                                       const float* __restrict__ w,
                                                       const float* __restrict__ bias,
                                                       float* __restrict__ out) {
    size_t idx = (size_t)blockIdx.x * 256 + threadIdx.x;
    int m = (int)(idx / N_DIM), n = (int)(idx % N_DIM);
    float s = 0.f;
    for (int k = 0; k < K_DIM; ++k)
        s += x[(size_t)m * K_DIM + k] * w[(size_t)k * N_DIM + n];
    out[idx] = s + bias[n];
}

extern "C" void kernel_launch(void* const* d_in, const int* in_sizes, int n_in,
                              void* d_out, int out_size, void* d_ws, size_t ws_size,
                              hipStream_t stream) {
    const float* x    = (const float*)d_in[0];
    const float* w    = (const float*)d_in[1];
    const float* bias = (const float*)d_in[2];
    float* out = (float*)d_out;

    size_t need = (size_t)M_TOK * K_DIM * 2 + (size_t)K_DIM * N_DIM * 2;
    if (ws_size >= need) {
        u16* xb = (u16*)d_ws;                      // [M][K] bf16
        u16* wt = xb + (size_t)M_TOK * K_DIM;      // [N][K] bf16
        cvt_kernel<<<(M_TOK * (size_t)K_DIM) / (256 * 8), 256, 0, stream>>>(x, xb);
        transpose_cvt_kernel<<<dim3(K_DIM / 64, N_DIM / 64), 256, 0, stream>>>(w, wt);
        gemm_kernel<<<(M_TOK / 128) * (N_DIM / 128), 256, 0, stream>>>(xb, wt, bias, out);
    } else {
        fallback_kernel<<<((size_t)M_TOK * N_DIM) / 256, 256, 0, stream>>>(x, w, bias, out);
    }
}

// Round 3
// 484.549 us; speedup vs baseline: 1.2546x; 1.2546x over previous
//
#include <hip/hip_runtime.h>
#include <hip/hip_bf16.h>

#define M_TOK 8192
#define K_DIM 4096
#define N_DIM 4096
#define NTILES (K_DIM / 64)   // 64 K-tiles of BK=64

typedef float f32x4 __attribute__((ext_vector_type(4)));
typedef __bf16 bf16x8 __attribute__((ext_vector_type(8)));
typedef unsigned short u16;

__device__ __forceinline__ u16 f2bf(float f) {
    union { float f; unsigned u; } v; v.f = f;
    unsigned r = v.u + 0x7FFF + ((v.u >> 16) & 1);   // RTNE
    return (u16)(r >> 16);
}

__device__ __forceinline__ void gload16(const void* g, void* l) {
    __builtin_amdgcn_global_load_lds(
        (const __attribute__((address_space(1))) unsigned*)g,
        (__attribute__((address_space(3))) unsigned*)l, 16, 0, 0);
}

#define BAR() __builtin_amdgcn_s_barrier()
#define LGKM0() do { asm volatile("s_waitcnt lgkmcnt(0)" ::: "memory"); \
                     __builtin_amdgcn_sched_barrier(0); } while (0)
#define VMC(n) asm volatile("s_waitcnt vmcnt(" #n ")" ::: "memory")

// ---- pre-pass: x fp32 -> bf16 ----
__global__ __launch_bounds__(256) void cvt_kernel(const float* __restrict__ in,
                                                  u16* __restrict__ out) {
    size_t i = ((size_t)blockIdx.x * 256 + threadIdx.x) * 8;
    const float4* p = (const float4*)(in + i);
    float4 a = p[0], b = p[1];
    union { u16 h[8]; uint4 v; } o;
    o.h[0] = f2bf(a.x); o.h[1] = f2bf(a.y); o.h[2] = f2bf(a.z); o.h[3] = f2bf(a.w);
    o.h[4] = f2bf(b.x); o.h[5] = f2bf(b.y); o.h[6] = f2bf(b.z); o.h[7] = f2bf(b.w);
    *(uint4*)(out + i) = o.v;
}

// ---- pre-pass: W[k][n] fp32 -> Wt[n][k] bf16, 16B/lane both sides ----
__global__ __launch_bounds__(256) void transpose_cvt_kernel(const float* __restrict__ w,
                                                            u16* __restrict__ wt) {
    __shared__ float t[64][65];
    int k0 = blockIdx.x * 64, n0 = blockIdx.y * 64;
    int tid = threadIdx.x;
    int tx = tid & 15, ty = tid >> 4;          // 16 x 16; float4 reads
#pragma unroll
    for (int it = 0; it < 4; ++it) {
        int r = ty + it * 16;
        float4 v = *(const float4*)&w[(size_t)(k0 + r) * N_DIM + n0 + tx * 4];
        t[r][tx * 4 + 0] = v.x; t[r][tx * 4 + 1] = v.y;
        t[r][tx * 4 + 2] = v.z; t[r][tx * 4 + 3] = v.w;
    }
    __syncthreads();
    int kc = (tid & 7) * 8, nr0 = tid >> 3;    // 16B (8 x bf16) writes
#pragma unroll
    for (int it = 0; it < 2; ++it) {
        int nr = nr0 + it * 32;
        union { u16 h[8]; uint4 v; } o;
#pragma unroll
        for (int j = 0; j < 8; ++j) o.h[j] = f2bf(t[kc + j][nr]);
        *(uint4*)&wt[(size_t)(n0 + nr) * K_DIM + k0 + kc] = o.v;
    }
}

// ---- 256x256 / BK=64 / 8-wave / 8-phase GEMM (T2+T3+T4+T5) ----
// C[m][n] = sum_k A[m][k] * Bt[n][k] + bias[n]
// LDS per buf: A tile [256][64]bf16 at 0, B tile at 32768. XOR-swizzle
// kb ^ ((row&7)<<4): applied on the GLOBAL source (linear gload_lds dest)
// and on ds_read addresses (both-sides-or-neither, rule 21).
__global__ __launch_bounds__(512, 2) void gemm_kernel(const u16* __restrict__ A,
                                                      const u16* __restrict__ Bt,
                                                      const float* __restrict__ bias,
                                                      float* __restrict__ C) {
    __shared__ __align__(16) unsigned char lds[2][65536];

    int tid = threadIdx.x;
    int bid = blockIdx.x;
    // 512 blocks, bijective XCD swizzle (512 % 8 == 0), chunk = 64
    int swz = (bid & 7) * 64 + (bid >> 3);
    int by = swz >> 4;      // 0..31
    int bx = swz & 15;      // 0..15

    int lane = tid & 63, wid = tid >> 6;
    int wr = wid >> 2;      // 0..1  (M)
    int wc = wid & 3;       // 0..3  (N)
    int frow = lane & 15;
    int ksegb = (lane >> 4) * 16;        // 0,16,32,48 bytes
    int xorv = (frow & 7) << 4;          // swizzle term (row&7 == frow&7)

    // staging constants: thread writes 16B at lds[buf][ht*16384 + tid*16] (+8192)
    // row_in_ht = tid>>3 (+64), kb_lds = (tid&7)*16; source kb = kb_lds ^ ((row&7)<<4)
    int srow = tid >> 3;
    int ske = (((tid & 7) * 16) ^ ((srow & 7) << 4)) >> 1;   // elements
    const u16* gA = A  + (size_t)(by * 256 + srow) * K_DIM + ske;
    const u16* gB = Bt + (size_t)(bx * 256 + srow) * K_DIM + ske;

    f32x4 acc[8][4] = {};
    bf16x8 a[4][2], b0[2][2], b1[2][2];

    auto STAGE = [&](int t, int ht) {
        const u16* src = (ht < 2) ? gA : gB;
        src += (size_t)((ht & 1) * 128) * K_DIM + t * 64;
        unsigned char* dst = &lds[t & 1][ht * 16384 + tid * 16];
        gload16(src, dst);
        gload16(src + (size_t)64 * K_DIM, dst + 8192);
    };
    auto LDA = [&](int buf, int mh) {
#pragma unroll
        for (int mf = 0; mf < 4; ++mf)
#pragma unroll
            for (int ks = 0; ks < 2; ++ks) {
                int r = wr * 128 + mh * 64 + mf * 16 + frow;
                a[mf][ks] = *(const bf16x8*)&lds[buf][(r << 7) + ((ksegb + ks * 64) ^ xorv)];
            }
    };
    auto LDB = [&](int buf, int nh, bf16x8 (&b)[2][2]) {
#pragma unroll
        for (int nf = 0; nf < 2; ++nf)
#pragma unroll
            for (int ks = 0; ks < 2; ++ks) {
                int r = wc * 64 + nh * 32 + nf * 16 + frow;
                b[nf][ks] = *(const bf16x8*)&lds[buf][32768 + (r << 7) + ((ksegb + ks * 64) ^ xorv)];
            }
    };
    auto MFMA = [&](int mh, int nh, bf16x8 (&b)[2][2]) {
        __builtin_amdgcn_s_setprio(1);
#pragma unroll
        for (int mf = 0; mf < 4; ++mf)
#pragma unroll
            for (int nf = 0; nf < 2; ++nf)
#pragma unroll
                for (int ks = 0; ks < 2; ++ks)
                    acc[mh * 4 + mf][nh * 2 + nf] = __builtin_amdgcn_mfma_f32_16x16x32_bf16(
                        a[mf][ks], b[nf][ks], acc[mh * 4 + mf][nh * 2 + nf], 0, 0, 0);
        __builtin_amdgcn_s_setprio(0);
    };

    // prologue: tile0 all 4 HT -> buf0; tile1 HT0 -> buf1; wait tile0 done
    STAGE(0, 0); STAGE(0, 1); STAGE(0, 2); STAGE(0, 3);
    STAGE(1, 0);
    VMC(2); BAR();

    for (int i = 0; i < NTILES / 2; ++i) {
        int e = 2 * i, o = 2 * i + 1;
        int e2 = (e + 2) & (NTILES - 1);     // wrap-around prefetch at tail (harmless)
        int o2 = (o + 2) & (NTILES - 1);
        // Ph1: tile e q(0,0)
        LDA(0, 0); LDB(0, 0, b0);
        STAGE(o, 1);
        BAR(); LGKM0();
        MFMA(0, 0, b0);
        BAR();
        // Ph2: q(0,1)
        LDB(0, 1, b1);
        STAGE(o, 2);
        BAR(); LGKM0();
        MFMA(0, 1, b1);
        BAR();
        // Ph3: q(1,0)
        LDA(0, 1);
        STAGE(o, 3);
        BAR(); LGKM0();
        MFMA(1, 0, b0);
        BAR();
        // Ph4: q(1,1); buf0 fully consumed after Ph3 -> start refilling it
        STAGE(e2, 0);
        VMC(2);            // all of tile o landed; e2-HT0 stays in flight
        BAR();
        MFMA(1, 1, b1);
        BAR();
        // Ph5: tile o q(0,0)
        LDA(1, 0); LDB(1, 0, b0);
        STAGE(e2, 1);
        BAR(); LGKM0();
        MFMA(0, 0, b0);
        BAR();
        // Ph6: q(0,1)
        LDB(1, 1, b1);
        STAGE(e2, 2);
        BAR(); LGKM0();
        MFMA(0, 1, b1);
        BAR();
        // Ph7: q(1,0)
        LDA(1, 1);
        STAGE(e2, 3);
        BAR(); LGKM0();
        MFMA(1, 0, b0);
        BAR();
        // Ph8: q(1,1); buf1 consumed after Ph7 -> refill
        STAGE(o2, 0);
        VMC(2);            // all of tile e2 landed; o2-HT0 stays in flight
        BAR();
        MFMA(1, 1, b1);
        BAR();
    }

    // epilogue: C/D layout col = lane&15, row = (lane>>4)*4 + reg
    int crow0 = by * 256 + wr * 128 + (lane >> 4) * 4;
    int ccol0 = bx * 256 + wc * 64 + (lane & 15);
    float bv[4];
#pragma unroll
    for (int nf = 0; nf < 4; ++nf) bv[nf] = bias[ccol0 + nf * 16];
#pragma unroll
    for (int mi = 0; mi < 8; ++mi)
#pragma unroll
        for (int nf = 0; nf < 4; ++nf)
#pragma unroll
            for (int r = 0; r < 4; ++r)
                C[(size_t)(crow0 + mi * 16 + r) * N_DIM + ccol0 + nf * 16] = acc[mi][nf][r] + bv[nf];
}

// ---- fallback (only if ws too small): naive fp32 ----
__global__ __launch_bounds__(256) void fallback_kernel(const float* __restrict__ x,
                                                       const float* __restrict__ w,
                                                       const float* __restrict__ bias,
                                                       float* __restrict__ out) {
    size_t idx = (size_t)blockIdx.x * 256 + threadIdx.x;
    int m = (int)(idx / N_DIM), n = (int)(idx % N_DIM);
    float s = 0.f;
    for (int k = 0; k < K_DIM; ++k)
        s += x[(size_t)m * K_DIM + k] * w[(size_t)k * N_DIM + n];
    out[idx] = s + bias[n];
}

extern "C" void kernel_launch(void* const* d_in, const int* in_sizes, int n_in,
                              void* d_out, int out_size, void* d_ws, size_t ws_size,
                              hipStream_t stream) {
    const float* x    = (const float*)d_in[0];
    const float* w    = (const float*)d_in[1];
    const float* bias = (const float*)d_in[2];
    float* out = (float*)d_out;

    size_t need = (size_t)M_TOK * K_DIM * 2 + (size_t)K_DIM * N_DIM * 2;
    if (ws_size >= need) {
        u16* xb = (u16*)d_ws;                      // [M][K] bf16
        u16* wt = xb + (size_t)M_TOK * K_DIM;      // [N][K] bf16
        cvt_kernel<<<(M_TOK * (size_t)K_DIM) / (256 * 8), 256, 0, stream>>>(x, xb);
        transpose_cvt_kernel<<<dim3(K_DIM / 64, N_DIM / 64), 256, 0, stream>>>(w, wt);
        gemm_kernel<<<(M_TOK / 256) * (N_DIM / 256), 512, 0, stream>>>(xb, wt, bias, out);
    } else {
        fallback_kernel<<<((size_t)M_TOK * N_DIM) / 256, 256, 0, stream>>>(x, w, bias, out);
    }
}